// Round 1
// baseline (309.117 us; speedup 1.0000x reference)
//
#include <hip/hip_runtime.h>

typedef unsigned short u16;
typedef __attribute__((ext_vector_type(8))) unsigned short u16x8;
typedef __attribute__((ext_vector_type(8))) short s16x8;
typedef __attribute__((ext_vector_type(4))) float f32x4;

__device__ __forceinline__ u16 f2bf(float f) {
    union { float f; unsigned int u; } c; c.f = f;
    unsigned int u = c.u;
    u += 0x7fffu + ((u >> 16) & 1u);   // RNE
    return (u16)(u >> 16);
}

// ---------------- cast fp32 -> bf16, 8 elems/thread ----------------
__global__ __launch_bounds__(256) void cast_f32_bf16(const float* __restrict__ in,
                                                     u16* __restrict__ out, int n8) {
    int i = blockIdx.x * 256 + threadIdx.x;
    if (i >= n8) return;
    const float4* p = (const float4*)in;
    float4 a = p[2 * i], b = p[2 * i + 1];
    u16x8 o;
    o[0] = f2bf(a.x); o[1] = f2bf(a.y); o[2] = f2bf(a.z); o[3] = f2bf(a.w);
    o[4] = f2bf(b.x); o[5] = f2bf(b.y); o[6] = f2bf(b.z); o[7] = f2bf(b.w);
    ((u16x8*)out)[i] = o;
}

// ---------------- transpose+cast: src fp32 [R][C] -> dst bf16 [C][R] ----------------
__global__ __launch_bounds__(256) void transpose_cast_f32(const float* __restrict__ src,
                                                          u16* __restrict__ dst, int R, int C) {
    __shared__ u16 t[32][33];
    int tx = threadIdx.x & 31, ty = threadIdx.x >> 5;
    int c0 = blockIdx.x * 32, r0 = blockIdx.y * 32;
#pragma unroll
    for (int i = 0; i < 4; ++i)
        t[ty + i * 8][tx] = f2bf(src[(size_t)(r0 + ty + i * 8) * C + c0 + tx]);
    __syncthreads();
#pragma unroll
    for (int i = 0; i < 4; ++i)
        dst[(size_t)(c0 + ty + i * 8) * R + r0 + tx] = t[tx][ty + i * 8];
}

// ---------------- transpose bf16 [R][C] -> [C][R], batched over blockIdx.z ----------------
__global__ __launch_bounds__(256) void transpose_b16(const u16* __restrict__ src,
                                                     u16* __restrict__ dst, int R, int C) {
    src += (size_t)blockIdx.z * R * C;
    dst += (size_t)blockIdx.z * R * C;
    __shared__ u16 t[32][33];
    int tx = threadIdx.x & 31, ty = threadIdx.x >> 5;
    int c0 = blockIdx.x * 32, r0 = blockIdx.y * 32;
#pragma unroll
    for (int i = 0; i < 4; ++i)
        t[ty + i * 8][tx] = src[(size_t)(r0 + ty + i * 8) * C + c0 + tx];
    __syncthreads();
#pragma unroll
    for (int i = 0; i < 4; ++i)
        dst[(size_t)(c0 + ty + i * 8) * R + r0 + tx] = t[tx][ty + i * 8];
}

// ---------------- row softmax over 2048 cols, in-place fp32 -> bf16 (row stride 4096 u16) ----
__global__ __launch_bounds__(256) void softmax_rows(float* __restrict__ S) {
    const int t = threadIdx.x;
    float* row = S + (size_t)blockIdx.x * 2048;
    const float4* rv = (const float4*)row;
    float4 a = rv[2 * t], b = rv[2 * t + 1];
    float m = fmaxf(fmaxf(fmaxf(a.x, a.y), fmaxf(a.z, a.w)),
                    fmaxf(fmaxf(b.x, b.y), fmaxf(b.z, b.w)));
#pragma unroll
    for (int o = 32; o >= 1; o >>= 1) m = fmaxf(m, __shfl_xor(m, o));
    __shared__ float sm[4], ss[4];
    if ((t & 63) == 0) sm[t >> 6] = m;
    __syncthreads();   // also guarantees all row loads complete before in-place writes
    m = fmaxf(fmaxf(sm[0], sm[1]), fmaxf(sm[2], sm[3]));
    float e0 = __expf(a.x - m), e1 = __expf(a.y - m), e2 = __expf(a.z - m), e3 = __expf(a.w - m);
    float e4 = __expf(b.x - m), e5 = __expf(b.y - m), e6 = __expf(b.z - m), e7 = __expf(b.w - m);
    float s = ((e0 + e1) + (e2 + e3)) + ((e4 + e5) + (e6 + e7));
#pragma unroll
    for (int o = 32; o >= 1; o >>= 1) s += __shfl_xor(s, o);
    if ((t & 63) == 0) ss[t >> 6] = s;
    __syncthreads();
    s = (ss[0] + ss[1]) + (ss[2] + ss[3]);
    float inv = 1.f / s;
    u16x8 o8;
    o8[0] = f2bf(e0 * inv); o8[1] = f2bf(e1 * inv); o8[2] = f2bf(e2 * inv); o8[3] = f2bf(e3 * inv);
    o8[4] = f2bf(e4 * inv); o8[5] = f2bf(e5 * inv); o8[6] = f2bf(e6 * inv); o8[7] = f2bf(e7 * inv);
    ((u16x8*)row)[t] = o8;
}

// ---------------- bf16 GEMM: C[M,N] = A[M,K] * Bt[N,K]^T ----------------
// 128x128 tile, BK=64, 256 threads = 4 waves (2x2), each wave 64x64 = 4x4 frags of 16x16x32.
// LDS tiles [128][64] bf16 with XOR swizzle: byte = row*128 + (colbyte ^ ((row&7)<<4)).
// EPI 0: QKV split+bias (+fold 1/32 into Q)   1: fp32 store   2: bf16 store   3: bias + fp32 store
template<int EPI>
__global__ __launch_bounds__(256) void gemm_bt(
    const u16* __restrict__ A, const u16* __restrict__ Bt,
    int K, int ldA, int ldBt,
    const float* __restrict__ bias,
    float* __restrict__ outF, int ldOutF,
    u16* __restrict__ outH, int ldOutH,
    u16* __restrict__ Qo, u16* __restrict__ Ko, u16* __restrict__ Vo) {
    __shared__ u16 sA[128 * 64];
    __shared__ u16 sB[128 * 64];
    const int tid = threadIdx.x;
    const int lane = tid & 63;
    const int wave = tid >> 6;
    const int wrow = wave >> 1, wcol = wave & 1;
    const int bm0 = blockIdx.x * 128;
    const int bn0 = blockIdx.y * 128;

    // staging: 4 chunks of 16B per thread per tile (1024 chunks = 128 rows x 128B)
    const int sr = tid >> 3;            // row within 32-row group
    const int scb = (tid & 7) * 16;     // byte col in row
    const int sce = scb >> 1;           // elem col
    const u16* aPtr[4];
    const u16* bPtr[4];
    int ldsOff[4];
#pragma unroll
    for (int it = 0; it < 4; ++it) {
        int r = sr + it * 32;
        aPtr[it] = A + (size_t)(bm0 + r) * ldA + sce;
        bPtr[it] = Bt + (size_t)(bn0 + r) * ldBt + sce;
        ldsOff[it] = r * 64 + ((scb ^ ((r & 7) << 4)) >> 1);
    }

    f32x4 acc[4][4] = {};
    const int lrow = lane & 15;
    const int lkg = lane >> 4;          // k-group 0..3

    const int NT = K >> 6;
    u16x8 ra[4], rb[4];
#pragma unroll
    for (int it = 0; it < 4; ++it) {
        ra[it] = *(const u16x8*)aPtr[it];
        rb[it] = *(const u16x8*)bPtr[it];
    }

    for (int kt = 0; kt < NT; ++kt) {
        __syncthreads();                 // previous tile's ds_reads done
#pragma unroll
        for (int it = 0; it < 4; ++it) {
            *(u16x8*)(sA + ldsOff[it]) = ra[it];
            *(u16x8*)(sB + ldsOff[it]) = rb[it];
        }
        __syncthreads();
        if (kt + 1 < NT) {               // prefetch next tile into regs (hidden under MFMAs)
#pragma unroll
            for (int it = 0; it < 4; ++it) {
                ra[it] = *(const u16x8*)(aPtr[it] + (size_t)(kt + 1) * 64);
                rb[it] = *(const u16x8*)(bPtr[it] + (size_t)(kt + 1) * 64);
            }
        }
#pragma unroll
        for (int ks = 0; ks < 2; ++ks) {
            s16x8 af[4], bf[4];
            const int colb = ks * 64 + lkg * 16;
#pragma unroll
            for (int i = 0; i < 4; ++i) {
                int ar = wrow * 64 + i * 16 + lrow;
                af[i] = *(const s16x8*)(sA + ar * 64 + ((colb ^ ((ar & 7) << 4)) >> 1));
                int br = wcol * 64 + i * 16 + lrow;
                bf[i] = *(const s16x8*)(sB + br * 64 + ((colb ^ ((br & 7) << 4)) >> 1));
            }
#pragma unroll
            for (int i = 0; i < 4; ++i)
#pragma unroll
                for (int j = 0; j < 4; ++j)
                    acc[i][j] = __builtin_amdgcn_mfma_f32_16x16x32_bf16(af[i], bf[j], acc[i][j], 0, 0, 0);
        }
    }

    // epilogue: C/D frag layout col = lane&15, row = (lane>>4)*4 + reg  [m89-verified]
#pragma unroll
    for (int i = 0; i < 4; ++i) {
        int row0 = bm0 + wrow * 64 + i * 16 + lkg * 4;
#pragma unroll
        for (int j = 0; j < 4; ++j) {
            int col = bn0 + wcol * 64 + j * 16 + lrow;
#pragma unroll
            for (int r = 0; r < 4; ++r) {
                int row = row0 + r;
                float v = acc[i][j][r];
                if constexpr (EPI == 0) {
                    v += bias[col];
                    if (col < 1024)       Qo[(size_t)row * 1024 + col] = f2bf(v * 0.03125f);
                    else if (col < 2048)  Ko[(size_t)row * 1024 + (col - 1024)] = f2bf(v);
                    else                  Vo[(size_t)row * 1024 + (col - 2048)] = f2bf(v);
                } else if constexpr (EPI == 1) {
                    outF[(size_t)row * ldOutF + col] = v;
                } else if constexpr (EPI == 2) {
                    outH[(size_t)row * ldOutH + col] = f2bf(v);
                } else {
                    outF[(size_t)row * ldOutF + col] = v + bias[col];
                }
            }
        }
    }
}

extern "C" void kernel_launch(void* const* d_in, const int* in_sizes, int n_in,
                              void* d_out, int out_size, void* d_ws, size_t ws_size,
                              hipStream_t stream) {
    const float* x      = (const float*)d_in[0];
    const float* w_qkv  = (const float*)d_in[1];
    const float* b_qkv  = (const float*)d_in[2];
    const float* w_proj = (const float*)d_in[3];
    const float* b_proj = (const float*)d_in[4];
    float* out = (float*)d_out;
    char* ws = (char*)d_ws;
    (void)in_sizes; (void)n_in; (void)out_size;

    const size_t MB16 = 16777216;       // 8192*1024*2 bytes (bf16 [8192][1024])
    const size_t BATCH = 2097152;       // per-batch elements (2048*1024)

    if (ws_size >= 85983232) {
        // ---- batched plan (82 MB) ----
        u16*  xb     = (u16*)(ws);                         // later reused as Vt
        u16*  Qb     = (u16*)(ws + MB16);
        u16*  Kb     = (u16*)(ws + 2 * MB16);
        u16*  Vb     = (u16*)(ws + 3 * MB16);              // later reused as O
        float* Sb    = (float*)(ws + 4 * MB16);            // 16.78 MB, per-batch S / in-place P
        u16*  wqkvT  = (u16*)(ws + 4 * MB16);              // overlaps Sb; dead before S written
        u16*  wprojT = (u16*)(ws + 5 * MB16);
        u16*  Vt     = xb;
        u16*  Ob     = Vb;

        cast_f32_bf16<<<4096, 256, 0, stream>>>(x, xb, 1048576);
        transpose_cast_f32<<<dim3(96, 32), 256, 0, stream>>>(w_qkv, wqkvT, 1024, 3072);
        transpose_cast_f32<<<dim3(32, 32), 256, 0, stream>>>(w_proj, wprojT, 1024, 1024);
        gemm_bt<0><<<dim3(64, 24), 256, 0, stream>>>(xb, wqkvT, 1024, 1024, 1024,
                                                     b_qkv, nullptr, 0, nullptr, 0, Qb, Kb, Vb);
        transpose_b16<<<dim3(32, 64, 4), 256, 0, stream>>>(Vb, Vt, 2048, 1024);
        for (int b = 0; b < 4; ++b) {
            gemm_bt<1><<<dim3(16, 16), 256, 0, stream>>>(Qb + b * BATCH, Kb + b * BATCH,
                                                         1024, 1024, 1024, nullptr,
                                                         Sb, 2048, nullptr, 0,
                                                         nullptr, nullptr, nullptr);
            softmax_rows<<<2048, 256, 0, stream>>>(Sb);
            gemm_bt<2><<<dim3(16, 8), 256, 0, stream>>>((const u16*)Sb, Vt + b * BATCH,
                                                        2048, 4096, 2048, nullptr,
                                                        nullptr, 0, Ob + b * BATCH, 1024,
                                                        nullptr, nullptr, nullptr);
        }
        gemm_bt<3><<<dim3(64, 8), 256, 0, stream>>>(Ob, wprojT, 1024, 1024, 1024,
                                                    b_proj, out, 1024, nullptr, 0,
                                                    nullptr, nullptr, nullptr);
    } else {
        // ---- low-memory per-batch plan (44 MB) ----
        u16*  xbB    = (u16*)(ws);                         // 4.19 MB, reused as O per batch
        u16*  QbB    = (u16*)(ws + 4194304);
        u16*  KbB    = (u16*)(ws + 8388608);
        u16*  VbB    = (u16*)(ws + 12582912);
        u16*  VtB    = (u16*)(ws + 16777216);
        float* Sb    = (float*)(ws + 20971520);
        u16*  wqkvT  = (u16*)(ws + 37748736);
        u16*  wprojT = (u16*)(ws + 44040192);
        u16*  ObB    = xbB;

        transpose_cast_f32<<<dim3(96, 32), 256, 0, stream>>>(w_qkv, wqkvT, 1024, 3072);
        transpose_cast_f32<<<dim3(32, 32), 256, 0, stream>>>(w_proj, wprojT, 1024, 1024);
        for (int b = 0; b < 4; ++b) {
            cast_f32_bf16<<<1024, 256, 0, stream>>>(x + b * BATCH, xbB, 262144);
            gemm_bt<0><<<dim3(16, 24), 256, 0, stream>>>(xbB, wqkvT, 1024, 1024, 1024,
                                                         b_qkv, nullptr, 0, nullptr, 0,
                                                         QbB, KbB, VbB);
            transpose_b16<<<dim3(32, 64, 1), 256, 0, stream>>>(VbB, VtB, 2048, 1024);
            gemm_bt<1><<<dim3(16, 16), 256, 0, stream>>>(QbB, KbB, 1024, 1024, 1024, nullptr,
                                                         Sb, 2048, nullptr, 0,
                                                         nullptr, nullptr, nullptr);
            softmax_rows<<<2048, 256, 0, stream>>>(Sb);
            gemm_bt<2><<<dim3(16, 8), 256, 0, stream>>>((const u16*)Sb, VtB,
                                                        2048, 4096, 2048, nullptr,
                                                        nullptr, 0, ObB, 1024,
                                                        nullptr, nullptr, nullptr);
            gemm_bt<3><<<dim3(16, 8), 256, 0, stream>>>(ObB, wprojT, 1024, 1024, 1024,
                                                        b_proj, out + b * BATCH, 1024,
                                                        nullptr, 0, nullptr, nullptr, nullptr);
        }
    }
}

// Round 2
// 260.976 us; speedup vs baseline: 1.1845x; 1.1845x over previous
//
#include <hip/hip_runtime.h>

typedef unsigned short u16;
typedef __attribute__((ext_vector_type(8))) unsigned short u16x8;
typedef __attribute__((ext_vector_type(8))) short s16x8;
typedef __attribute__((ext_vector_type(4))) float f32x4;

__device__ __forceinline__ u16 f2bf(float f) {
    union { float f; unsigned int u; } c; c.f = f;
    unsigned int u = c.u;
    u += 0x7fffu + ((u >> 16) & 1u);   // RNE
    return (u16)(u >> 16);
}
__device__ __forceinline__ float bf2f(u16 h) {
    union { unsigned int u; float f; } c; c.u = ((unsigned int)h) << 16; return c.f;
}

// async 16B global -> LDS (linear dest: wave-uniform base + lane*16)
__device__ __forceinline__ void gload16(const u16* g, u16* l) {
    __builtin_amdgcn_global_load_lds(
        (const __attribute__((address_space(1))) void*)g,
        (__attribute__((address_space(3))) void*)l, 16, 0, 0);
}

// ---------------- cast fp32 -> bf16, 8 elems/thread ----------------
__global__ __launch_bounds__(256) void cast_f32_bf16(const float* __restrict__ in,
                                                     u16* __restrict__ out, int n8) {
    int i = blockIdx.x * 256 + threadIdx.x;
    if (i >= n8) return;
    const float4* p = (const float4*)in;
    float4 a = p[2 * i], b = p[2 * i + 1];
    u16x8 o;
    o[0] = f2bf(a.x); o[1] = f2bf(a.y); o[2] = f2bf(a.z); o[3] = f2bf(a.w);
    o[4] = f2bf(b.x); o[5] = f2bf(b.y); o[6] = f2bf(b.z); o[7] = f2bf(b.w);
    ((u16x8*)out)[i] = o;
}

// ---------------- transpose+cast: src fp32 [R][C] -> dst bf16 [C][R] ----------------
__global__ __launch_bounds__(256) void transpose_cast_f32(const float* __restrict__ src,
                                                          u16* __restrict__ dst, int R, int C) {
    __shared__ u16 t[32][33];
    int tx = threadIdx.x & 31, ty = threadIdx.x >> 5;
    int c0 = blockIdx.x * 32, r0 = blockIdx.y * 32;
#pragma unroll
    for (int i = 0; i < 4; ++i)
        t[ty + i * 8][tx] = f2bf(src[(size_t)(r0 + ty + i * 8) * C + c0 + tx]);
    __syncthreads();
#pragma unroll
    for (int i = 0; i < 4; ++i)
        dst[(size_t)(c0 + ty + i * 8) * R + r0 + tx] = t[tx][ty + i * 8];
}

// ---------------- transpose bf16 [R][C] -> [C][R], batched over blockIdx.z ----------------
__global__ __launch_bounds__(256) void transpose_b16(const u16* __restrict__ src,
                                                     u16* __restrict__ dst, int R, int C) {
    src += (size_t)blockIdx.z * R * C;
    dst += (size_t)blockIdx.z * R * C;
    __shared__ u16 t[32][33];
    int tx = threadIdx.x & 31, ty = threadIdx.x >> 5;
    int c0 = blockIdx.x * 32, r0 = blockIdx.y * 32;
#pragma unroll
    for (int i = 0; i < 4; ++i)
        t[ty + i * 8][tx] = src[(size_t)(r0 + ty + i * 8) * C + c0 + tx];
    __syncthreads();
#pragma unroll
    for (int i = 0; i < 4; ++i)
        dst[(size_t)(c0 + ty + i * 8) * R + r0 + tx] = t[tx][ty + i * 8];
}

// ---------------- row softmax over 2048 bf16 cols, in-place ----------------
__global__ __launch_bounds__(256) void softmax_rows_b16(u16* __restrict__ S) {
    const int t = threadIdx.x;
    u16* row = S + (size_t)blockIdx.x * 2048;
    u16x8 a = ((const u16x8*)row)[t];
    float f[8];
#pragma unroll
    for (int j = 0; j < 8; ++j) f[j] = bf2f(a[j]);
    float m = fmaxf(fmaxf(fmaxf(f[0], f[1]), fmaxf(f[2], f[3])),
                    fmaxf(fmaxf(f[4], f[5]), fmaxf(f[6], f[7])));
#pragma unroll
    for (int o = 32; o >= 1; o >>= 1) m = fmaxf(m, __shfl_xor(m, o));
    __shared__ float sm[4], ss[4];
    if ((t & 63) == 0) sm[t >> 6] = m;
    __syncthreads();
    m = fmaxf(fmaxf(sm[0], sm[1]), fmaxf(sm[2], sm[3]));
    float s = 0.f;
#pragma unroll
    for (int j = 0; j < 8; ++j) { f[j] = __expf(f[j] - m); s += f[j]; }
#pragma unroll
    for (int o = 32; o >= 1; o >>= 1) s += __shfl_xor(s, o);
    if ((t & 63) == 0) ss[t >> 6] = s;
    __syncthreads();
    s = (ss[0] + ss[1]) + (ss[2] + ss[3]);
    float inv = 1.f / s;
    u16x8 o8;
#pragma unroll
    for (int j = 0; j < 8; ++j) o8[j] = f2bf(f[j] * inv);
    ((u16x8*)row)[t] = o8;
}

// ---------------- bf16 GEMM: C[M,N] = A[M,K] * Bt[N,K]^T ----------------
// 128x128 tile, BK=64, 4 waves (2x2), each wave 64x64 = 4x4 frags of 16x16x32.
// Staging: global_load_lds width 16, LINEAR LDS dest; XOR swizzle applied to the
// per-lane GLOBAL source byte-col (involution), reads swizzled as before (rule #21).
// EPI 0: QKV split+bias (+fold 1/32 into Q)   2: bf16 store   3: bias + fp32 store
template<int EPI>
__global__ __launch_bounds__(256) void gemm_bt(
    const u16* __restrict__ A, const u16* __restrict__ Bt,
    int K, int ldA, int ldBt,
    const float* __restrict__ bias,
    float* __restrict__ outF, int ldOutF,
    u16* __restrict__ outH, int ldOutH,
    u16* __restrict__ Qo, u16* __restrict__ Ko, u16* __restrict__ Vo,
    size_t zA, size_t zBt, size_t zOut) {
    __shared__ u16 sA[128 * 64];
    __shared__ u16 sB[128 * 64];
    const int tid = threadIdx.x;
    const int lane = tid & 63;
    const int wave = tid >> 6;
    const int wrow = wave >> 1, wcol = wave & 1;
    const int bm0 = blockIdx.x * 128;
    const int bn0 = blockIdx.y * 128;
    A  += zA  * blockIdx.z;
    Bt += zBt * blockIdx.z;

    // staging: 4 x 16B chunks per thread per tile; chunk ci covers row ci>>3, bytes (ci&7)*16
    const u16* aSrc[4];
    const u16* bSrc[4];
    int ldsOff[4];
#pragma unroll
    for (int it = 0; it < 4; ++it) {
        int c  = it * 256 + tid;
        int r  = c >> 3;
        int cb = (c & 7) * 16;
        int sb = cb ^ ((r & 7) << 4);          // pre-swizzled source col (involution)
        aSrc[it] = A  + (size_t)(bm0 + r) * ldA  + (sb >> 1);
        bSrc[it] = Bt + (size_t)(bn0 + r) * ldBt + (sb >> 1);
        ldsOff[it] = (it * 256 + (tid & ~63)) * 8;   // wave-uniform linear dest (u16 units)
    }

    f32x4 acc[4][4] = {};
    const int lrow = lane & 15;
    const int lkg = lane >> 4;
    const int NT = K >> 6;

    for (int kt = 0; kt < NT; ++kt) {
        const int ko = kt * 64;
#pragma unroll
        for (int it = 0; it < 4; ++it) {
            gload16(aSrc[it] + ko, sA + ldsOff[it]);
            gload16(bSrc[it] + ko, sB + ldsOff[it]);
        }
        __syncthreads();                 // vmcnt(0) drain + barrier: tile resident
#pragma unroll
        for (int ks = 0; ks < 2; ++ks) {
            s16x8 af[4], bf[4];
            const int colb = ks * 64 + lkg * 16;
#pragma unroll
            for (int i = 0; i < 4; ++i) {
                int ar = wrow * 64 + i * 16 + lrow;
                af[i] = *(const s16x8*)(sA + ar * 64 + ((colb ^ ((ar & 7) << 4)) >> 1));
                int br = wcol * 64 + i * 16 + lrow;
                bf[i] = *(const s16x8*)(sB + br * 64 + ((colb ^ ((br & 7) << 4)) >> 1));
            }
#pragma unroll
            for (int i = 0; i < 4; ++i)
#pragma unroll
                for (int j = 0; j < 4; ++j)
                    acc[i][j] = __builtin_amdgcn_mfma_f32_16x16x32_bf16(af[i], bf[j], acc[i][j], 0, 0, 0);
        }
        __syncthreads();                 // all reads done before next tile overwrites
    }

    // epilogue: C/D frag layout col = lane&15, row = (lane>>4)*4 + reg  [m89-verified]
    if (zOut) { outH += zOut * blockIdx.z; }
#pragma unroll
    for (int i = 0; i < 4; ++i) {
        int row0 = bm0 + wrow * 64 + i * 16 + lkg * 4;
#pragma unroll
        for (int j = 0; j < 4; ++j) {
            int col = bn0 + wcol * 64 + j * 16 + lrow;
#pragma unroll
            for (int r = 0; r < 4; ++r) {
                int row = row0 + r;
                float v = acc[i][j][r];
                if constexpr (EPI == 0) {
                    v += bias[col];
                    if (col < 1024)       Qo[(size_t)row * 1024 + col] = f2bf(v * 0.03125f);
                    else if (col < 2048)  Ko[(size_t)row * 1024 + (col - 1024)] = f2bf(v);
                    else                  Vo[(size_t)row * 1024 + (col - 2048)] = f2bf(v);
                } else if constexpr (EPI == 2) {
                    outH[(size_t)row * ldOutH + col] = f2bf(v);
                } else {
                    outF[(size_t)row * ldOutF + col] = v + bias[col];
                }
            }
        }
    }
}

extern "C" void kernel_launch(void* const* d_in, const int* in_sizes, int n_in,
                              void* d_out, int out_size, void* d_ws, size_t ws_size,
                              hipStream_t stream) {
    const float* x      = (const float*)d_in[0];
    const float* w_qkv  = (const float*)d_in[1];
    const float* b_qkv  = (const float*)d_in[2];
    const float* w_proj = (const float*)d_in[3];
    const float* b_proj = (const float*)d_in[4];
    float* out = (float*)d_out;
    char* ws = (char*)d_ws;
    (void)in_sizes; (void)n_in; (void)out_size;

    const size_t MB16 = 16777216;       // bf16 [8192][1024] bytes
    const size_t BATCH = 2097152;       // per-batch elements (2048*1024)
    const size_t SZB  = 4194304;        // per-batch S elements (2048*2048)

    if (ws_size >= 85983232) {
        // ---- batched plan (82 MB, same footprint as round 0) ----
        u16*  xb     = (u16*)(ws);                         // later reused as Vt
        u16*  Qb     = (u16*)(ws + MB16);
        u16*  Kb     = (u16*)(ws + 2 * MB16);
        u16*  Vb     = (u16*)(ws + 3 * MB16);              // later reused as O
        u16*  Sb     = (u16*)(ws + 4 * MB16);              // 2-batch bf16 S (16.78 MB)
        u16*  wqkvT  = (u16*)(ws + 4 * MB16);              // overlaps Sb; dead before S written
        u16*  wprojT = (u16*)(ws + 5 * MB16);
        u16*  Vt     = xb;
        u16*  Ob     = Vb;

        cast_f32_bf16<<<4096, 256, 0, stream>>>(x, xb, 1048576);
        transpose_cast_f32<<<dim3(96, 32), 256, 0, stream>>>(w_qkv, wqkvT, 1024, 3072);
        transpose_cast_f32<<<dim3(32, 32), 256, 0, stream>>>(w_proj, wprojT, 1024, 1024);
        gemm_bt<0><<<dim3(64, 24), 256, 0, stream>>>(xb, wqkvT, 1024, 1024, 1024,
                                                     b_qkv, nullptr, 0, nullptr, 0,
                                                     Qb, Kb, Vb, 0, 0, 0);
        transpose_b16<<<dim3(32, 64, 4), 256, 0, stream>>>(Vb, Vt, 2048, 1024);
        for (int g = 0; g < 2; ++g) {
            gemm_bt<2><<<dim3(16, 16, 2), 256, 0, stream>>>(
                Qb + (size_t)g * 2 * BATCH, Kb + (size_t)g * 2 * BATCH,
                1024, 1024, 1024, nullptr, nullptr, 0, Sb, 2048,
                nullptr, nullptr, nullptr, BATCH, BATCH, SZB);
            softmax_rows_b16<<<4096, 256, 0, stream>>>(Sb);
            gemm_bt<2><<<dim3(16, 8, 2), 256, 0, stream>>>(
                Sb, Vt + (size_t)g * 2 * BATCH,
                2048, 2048, 2048, nullptr, nullptr, 0, Ob + (size_t)g * 2 * BATCH, 1024,
                nullptr, nullptr, nullptr, SZB, BATCH, BATCH);
        }
        gemm_bt<3><<<dim3(64, 8), 256, 0, stream>>>(Ob, wprojT, 1024, 1024, 1024,
                                                    b_proj, out, 1024, nullptr, 0,
                                                    nullptr, nullptr, nullptr, 0, 0, 0);
    } else {
        // ---- low-memory per-batch plan (<=46 MB) ----
        u16*  xbB    = (u16*)(ws);                         // reused as O per batch
        u16*  QbB    = (u16*)(ws + 4194304);
        u16*  KbB    = (u16*)(ws + 8388608);
        u16*  VbB    = (u16*)(ws + 12582912);
        u16*  VtB    = (u16*)(ws + 16777216);
        u16*  Sb     = (u16*)(ws + 20971520);              // bf16 S (8.4 MB)
        u16*  wqkvT  = (u16*)(ws + 37748736);
        u16*  wprojT = (u16*)(ws + 44040192);
        u16*  ObB    = xbB;

        transpose_cast_f32<<<dim3(96, 32), 256, 0, stream>>>(w_qkv, wqkvT, 1024, 3072);
        transpose_cast_f32<<<dim3(32, 32), 256, 0, stream>>>(w_proj, wprojT, 1024, 1024);
        for (int b = 0; b < 4; ++b) {
            cast_f32_bf16<<<1024, 256, 0, stream>>>(x + (size_t)b * BATCH, xbB, 262144);
            gemm_bt<0><<<dim3(16, 24), 256, 0, stream>>>(xbB, wqkvT, 1024, 1024, 1024,
                                                         b_qkv, nullptr, 0, nullptr, 0,
                                                         QbB, KbB, VbB, 0, 0, 0);
            transpose_b16<<<dim3(32, 64, 1), 256, 0, stream>>>(VbB, VtB, 2048, 1024);
            gemm_bt<2><<<dim3(16, 16), 256, 0, stream>>>(QbB, KbB, 1024, 1024, 1024,
                                                         nullptr, nullptr, 0, Sb, 2048,
                                                         nullptr, nullptr, nullptr, 0, 0, 0);
            softmax_rows_b16<<<2048, 256, 0, stream>>>(Sb);
            gemm_bt<2><<<dim3(16, 8), 256, 0, stream>>>(Sb, VtB, 2048, 2048, 2048,
                                                        nullptr, nullptr, 0, ObB, 1024,
                                                        nullptr, nullptr, nullptr, 0, 0, 0);
            gemm_bt<3><<<dim3(16, 8), 256, 0, stream>>>(ObB, wprojT, 1024, 1024, 1024,
                                                        b_proj, out + (size_t)b * BATCH, 1024,
                                                        nullptr, 0, nullptr, nullptr, nullptr, 0, 0, 0);
        }
    }
}

// Round 3
// 238.001 us; speedup vs baseline: 1.2988x; 1.0965x over previous
//
#include <hip/hip_runtime.h>

typedef unsigned short u16;
typedef __attribute__((ext_vector_type(8))) unsigned short u16x8;
typedef __attribute__((ext_vector_type(8))) short s16x8;
typedef __attribute__((ext_vector_type(4))) float f32x4;

__device__ __forceinline__ u16 f2bf(float f) {
    union { float f; unsigned int u; } c; c.f = f;
    unsigned int u = c.u;
    u += 0x7fffu + ((u >> 16) & 1u);   // RNE
    return (u16)(u >> 16);
}
__device__ __forceinline__ float bf2f(u16 h) {
    union { unsigned int u; float f; } c; c.u = ((unsigned int)h) << 16; return c.f;
}

// async 16B global -> LDS (dest: wave-uniform base, HW adds lane*16)
__device__ __forceinline__ void gload16(const u16* g, u16* l) {
    __builtin_amdgcn_global_load_lds(
        (const __attribute__((address_space(1))) void*)g,
        (__attribute__((address_space(3))) void*)l, 16, 0, 0);
}

// ---------------- cast fp32 -> bf16, 8 elems/thread ----------------
__global__ __launch_bounds__(256) void cast_f32_bf16(const float* __restrict__ in,
                                                     u16* __restrict__ out, int n8) {
    int i = blockIdx.x * 256 + threadIdx.x;
    if (i >= n8) return;
    const float4* p = (const float4*)in;
    float4 a = p[2 * i], b = p[2 * i + 1];
    u16x8 o;
    o[0] = f2bf(a.x); o[1] = f2bf(a.y); o[2] = f2bf(a.z); o[3] = f2bf(a.w);
    o[4] = f2bf(b.x); o[5] = f2bf(b.y); o[6] = f2bf(b.z); o[7] = f2bf(b.w);
    ((u16x8*)out)[i] = o;
}

// ---------------- transpose+cast: src fp32 [R][C] -> dst bf16 [C][R] ----------------
__global__ __launch_bounds__(256) void transpose_cast_f32(const float* __restrict__ src,
                                                          u16* __restrict__ dst, int R, int C) {
    __shared__ u16 t[32][33];
    int tx = threadIdx.x & 31, ty = threadIdx.x >> 5;
    int c0 = blockIdx.x * 32, r0 = blockIdx.y * 32;
#pragma unroll
    for (int i = 0; i < 4; ++i)
        t[ty + i * 8][tx] = f2bf(src[(size_t)(r0 + ty + i * 8) * C + c0 + tx]);
    __syncthreads();
#pragma unroll
    for (int i = 0; i < 4; ++i)
        dst[(size_t)(c0 + ty + i * 8) * R + r0 + tx] = t[tx][ty + i * 8];
}

// ---------------- transpose bf16 [R][C] -> [C][R], batched over blockIdx.z ----------------
__global__ __launch_bounds__(256) void transpose_b16(const u16* __restrict__ src,
                                                     u16* __restrict__ dst, int R, int C) {
    src += (size_t)blockIdx.z * R * C;
    dst += (size_t)blockIdx.z * R * C;
    __shared__ u16 t[32][33];
    int tx = threadIdx.x & 31, ty = threadIdx.x >> 5;
    int c0 = blockIdx.x * 32, r0 = blockIdx.y * 32;
#pragma unroll
    for (int i = 0; i < 4; ++i)
        t[ty + i * 8][tx] = src[(size_t)(r0 + ty + i * 8) * C + c0 + tx];
    __syncthreads();
#pragma unroll
    for (int i = 0; i < 4; ++i)
        dst[(size_t)(c0 + ty + i * 8) * R + r0 + tx] = t[tx][ty + i * 8];
}

// ---------------- row softmax over 2048 bf16 cols, in-place ----------------
__global__ __launch_bounds__(256) void softmax_rows_b16(u16* __restrict__ S) {
    const int t = threadIdx.x;
    u16* row = S + (size_t)blockIdx.x * 2048;
    u16x8 a = ((const u16x8*)row)[t];
    float f[8];
#pragma unroll
    for (int j = 0; j < 8; ++j) f[j] = bf2f(a[j]);
    float m = fmaxf(fmaxf(fmaxf(f[0], f[1]), fmaxf(f[2], f[3])),
                    fmaxf(fmaxf(f[4], f[5]), fmaxf(f[6], f[7])));
#pragma unroll
    for (int o = 32; o >= 1; o >>= 1) m = fmaxf(m, __shfl_xor(m, o));
    __shared__ float sm[4], ss[4];
    if ((t & 63) == 0) sm[t >> 6] = m;
    __syncthreads();
    m = fmaxf(fmaxf(sm[0], sm[1]), fmaxf(sm[2], sm[3]));
    float s = 0.f;
#pragma unroll
    for (int j = 0; j < 8; ++j) { f[j] = __expf(f[j] - m); s += f[j]; }
#pragma unroll
    for (int o = 32; o >= 1; o >>= 1) s += __shfl_xor(s, o);
    if ((t & 63) == 0) ss[t >> 6] = s;
    __syncthreads();
    s = (ss[0] + ss[1]) + (ss[2] + ss[3]);
    float inv = 1.f / s;
    u16x8 o8;
#pragma unroll
    for (int j = 0; j < 8; ++j) o8[j] = f2bf(f[j] * inv);
    ((u16x8*)row)[t] = o8;
}

// ================= 256x256 8-phase bf16 GEMM: C = A[M,K] * Bt[N,K]^T =================
// 512 thr = 8 waves (2M x 4N); per wave 128x64 out = 8x4 frags of 16x16x32.
// LDS 128 KiB: 2 bufs x {A0,A1,B0,B1} halves (each 128 rows x 64 cols bf16 = 16 KB).
// Staging: gload16 linear dest + pre-swizzled global source; reads XOR-swizzled.
// Schedule per K-tile t (c=t&1): P1{rd A-q0,B-p0 | stage B1(t+1)} P2{rd B-p1 | stage A1(t+1)}
//   P3{rd A-q1 | stage B0(t+2)} P4{stage A0(t+2), vmcnt(4)} ; 16 MFMA per phase.
template<int MB, int NB>
__device__ __forceinline__ void mfma_quad(f32x4 (&acc)[8][4], const s16x8 (&ra)[4][2],
                                          const s16x8 (&rb)[2][2]) {
    __builtin_amdgcn_s_setprio(1);
#pragma unroll
    for (int ks = 0; ks < 2; ++ks)
#pragma unroll
        for (int i = 0; i < 4; ++i)
#pragma unroll
            for (int j = 0; j < 2; ++j)
                acc[MB + i][NB + j] = __builtin_amdgcn_mfma_f32_16x16x32_bf16(
                    ra[i][ks], rb[j][ks], acc[MB + i][NB + j], 0, 0, 0);
    __builtin_amdgcn_s_setprio(0);
}

__device__ __forceinline__ void read_frags4(const char* base, int rbase, int sc0, int sc1,
                                            s16x8 (&r)[4][2]) {
#pragma unroll
    for (int i = 0; i < 4; ++i) {
        const char* p = base + (rbase + i * 16) * 128;
        r[i][0] = *(const s16x8*)(p + sc0);
        r[i][1] = *(const s16x8*)(p + sc1);
    }
}
__device__ __forceinline__ void read_frags2(const char* base, int rbase, int sc0, int sc1,
                                            s16x8 (&r)[2][2]) {
#pragma unroll
    for (int j = 0; j < 2; ++j) {
        const char* p = base + (rbase + j * 16) * 128;
        r[j][0] = *(const s16x8*)(p + sc0);
        r[j][1] = *(const s16x8*)(p + sc1);
    }
}

// EPI 0: QKV split+bias (+fold 1/32 into Q)   2: bf16 store   3: bias + fp32 store
template<int EPI>
__global__ __launch_bounds__(512) void gemm256(
    const u16* __restrict__ A, const u16* __restrict__ Bt,
    int K, int ldA, int ldBt,
    const float* __restrict__ bias,
    float* __restrict__ outF, int ldOutF,
    u16* __restrict__ outH, int ldOutH,
    u16* __restrict__ Qo, u16* __restrict__ Ko, u16* __restrict__ Vo,
    size_t zA, size_t zBt, size_t zOut) {
    __shared__ u16 lds[65536];          // 128 KiB
    const int tid  = threadIdx.x;
    const int lane = tid & 63;
    const int wave = tid >> 6;          // 0..7
    const int wm   = wave >> 2;         // 0..1  (M half)
    const int wn   = wave & 3;          // 0..3  (N quarter)
    const int lrow = lane & 15;
    const int lkg  = lane >> 4;
    const int bm0  = blockIdx.x * 256;
    const int bn0  = blockIdx.y * 256;
    A  += zA  * blockIdx.z;
    Bt += zBt * blockIdx.z;

    // ---- staging source pointers (pre-swizzled col), h = row-half, L = 64-row sub ----
    const int srow = tid >> 3;                          // 0..63
    const int ssc  = (((tid & 7) * 16) ^ ((srow & 7) << 4)) >> 1;   // elem col
    const u16* aS[2][2];
    const u16* bS[2][2];
#pragma unroll
    for (int h = 0; h < 2; ++h)
#pragma unroll
        for (int L = 0; L < 2; ++L) {
            aS[h][L] = A  + (size_t)(bm0 + h * 128 + L * 64 + srow) * ldA  + ssc;
            bS[h][L] = Bt + (size_t)(bn0 + h * 128 + L * 64 + srow) * ldBt + ssc;
        }
    const int dwave = wave * 512;       // u16 units; lane*16B added by HW

    // LDS u16 offsets: buf*32768 + {A0:0, A1:8192, B0:16384, B1:24576} + L*4096 + dwave
#define STAGE_A(h, t, b)                                                            \
    { gload16(aS[h][0] + (size_t)(t) * 64, lds + (b) * 32768 + (h) * 8192 + dwave); \
      gload16(aS[h][1] + (size_t)(t) * 64, lds + (b) * 32768 + (h) * 8192 + 4096 + dwave); }
#define STAGE_B(h, t, b)                                                                    \
    { gload16(bS[h][0] + (size_t)(t) * 64, lds + (b) * 32768 + 16384 + (h) * 8192 + dwave); \
      gload16(bS[h][1] + (size_t)(t) * 64, lds + (b) * 32768 + 16384 + (h) * 8192 + 4096 + dwave); }

    // ---- read addressing ----
    const char* ldsc = (const char*)lds;
    const int sc0 = (lkg * 16) ^ ((lrow & 7) << 4);
    const int sc1 = (64 + lkg * 16) ^ ((lrow & 7) << 4);
    const int aHalf = wm * 16384;                 // byte offset of this wave's A half
    const int bHalf = 32768 + (wn >> 1) * 16384;  // byte offset of this wave's B half
    const int brow  = (wn & 1) * 64 + lrow;

    f32x4 acc[8][4] = {};
    s16x8 regA[4][2], regB0[2][2], regB1[2][2];
    const int NT = K >> 6;

    // ---- prologue: tile0 full + {B0,A0} of tile1 ----
    STAGE_A(0, 0, 0); STAGE_B(0, 0, 0); STAGE_B(1, 0, 0); STAGE_A(1, 0, 0);
    if (NT > 1) { STAGE_B(0, 1, 1); STAGE_A(0, 1, 1); }
    asm volatile("s_waitcnt vmcnt(4)" ::: "memory");
    __builtin_amdgcn_s_barrier();

    for (int t = 0; t < NT; ++t) {
        const int c = t & 1, o = c ^ 1;
        const char* baseA = ldsc + c * 65536 + aHalf;
        const char* baseB = ldsc + c * 65536 + bHalf;
        // ---- P1: quadrant (m0,n0) ----
        read_frags4(baseA, lrow, sc0, sc1, regA);
        read_frags2(baseB, brow, sc0, sc1, regB0);
        if (t + 1 < NT) STAGE_B(1, t + 1, o);
        __builtin_amdgcn_s_barrier();
        mfma_quad<0, 0>(acc, regA, regB0);
        __builtin_amdgcn_s_barrier();
        // ---- P2: quadrant (m0,n1) ----
        read_frags2(baseB, brow + 32, sc0, sc1, regB1);
        if (t + 1 < NT) STAGE_A(1, t + 1, o);
        __builtin_amdgcn_s_barrier();
        mfma_quad<0, 2>(acc, regA, regB1);
        __builtin_amdgcn_s_barrier();
        // ---- P3: quadrant (m1,n1) ----
        read_frags4(baseA, 64 + lrow, sc0, sc1, regA);
        if (t + 2 < NT) STAGE_B(0, t + 2, c);
        __builtin_amdgcn_s_barrier();
        mfma_quad<4, 2>(acc, regA, regB1);
        __builtin_amdgcn_s_barrier();
        // ---- P4: quadrant (m1,n0); counted vmcnt once per K-tile ----
        if (t + 2 < NT) STAGE_A(0, t + 2, c);
        __builtin_amdgcn_sched_barrier(0);
        asm volatile("s_waitcnt vmcnt(4)" ::: "memory");
        __builtin_amdgcn_sched_barrier(0);
        __builtin_amdgcn_s_barrier();
        mfma_quad<4, 0>(acc, regA, regB0);
        __builtin_amdgcn_s_barrier();
    }
#undef STAGE_A
#undef STAGE_B

    // ---- epilogue: C/D layout col = lane&15, row = (lane>>4)*4 + reg [m89-verified] ----
    if (zOut) outH += zOut * blockIdx.z;
#pragma unroll
    for (int mf = 0; mf < 8; ++mf) {
        int row0 = bm0 + wm * 128 + mf * 16 + lkg * 4;
#pragma unroll
        for (int nf = 0; nf < 4; ++nf) {
            int col = bn0 + wn * 64 + nf * 16 + lrow;
#pragma unroll
            for (int r = 0; r < 4; ++r) {
                int row = row0 + r;
                float v = acc[mf][nf][r];
                if constexpr (EPI == 0) {
                    v += bias[col];
                    if (col < 1024)       Qo[(size_t)row * 1024 + col] = f2bf(v * 0.03125f);
                    else if (col < 2048)  Ko[(size_t)row * 1024 + (col - 1024)] = f2bf(v);
                    else                  Vo[(size_t)row * 1024 + (col - 2048)] = f2bf(v);
                } else if constexpr (EPI == 2) {
                    outH[(size_t)row * ldOutH + col] = f2bf(v);
                } else {
                    outF[(size_t)row * ldOutF + col] = v + bias[col];
                }
            }
        }
    }
}

extern "C" void kernel_launch(void* const* d_in, const int* in_sizes, int n_in,
                              void* d_out, int out_size, void* d_ws, size_t ws_size,
                              hipStream_t stream) {
    const float* x      = (const float*)d_in[0];
    const float* w_qkv  = (const float*)d_in[1];
    const float* b_qkv  = (const float*)d_in[2];
    const float* w_proj = (const float*)d_in[3];
    const float* b_proj = (const float*)d_in[4];
    float* out = (float*)d_out;
    char* ws = (char*)d_ws;
    (void)in_sizes; (void)n_in; (void)out_size;

    const size_t MB16  = 16777216;      // bf16 [8192][1024] bytes
    const size_t BATCH = 2097152;       // per-batch elements (2048*1024)
    const size_t SZB   = 4194304;       // per-batch S elements (2048*2048)

    if (ws_size >= 85983232) {
        // ---- batched plan (83.9 MB) ----
        u16* xb     = (u16*)(ws);                    // -> Vt after QKV
        u16* Qb     = (u16*)(ws + MB16);             // -> Ob after S-GEMM
        u16* Kb     = (u16*)(ws + 2 * MB16);         // -> wprojT after S-GEMM
        u16* Vb     = (u16*)(ws + 3 * MB16);         // -> Sb (4 batches, 33.5 MB)
        u16* wqkvT  = (u16*)(ws + 4 * MB16);         // dead after QKV; Sb overwrites
        u16* Vt     = xb;
        u16* Ob     = Qb;
        u16* Sb     = Vb;
        u16* wprojT = Kb;

        cast_f32_bf16<<<4096, 256, 0, stream>>>(x, xb, 1048576);
        transpose_cast_f32<<<dim3(96, 32), 256, 0, stream>>>(w_qkv, wqkvT, 1024, 3072);
        gemm256<0><<<dim3(32, 12), 512, 0, stream>>>(xb, wqkvT, 1024, 1024, 1024,
                                                     b_qkv, nullptr, 0, nullptr, 0,
                                                     Qb, Kb, Vb, 0, 0, 0);
        transpose_b16<<<dim3(32, 64, 4), 256, 0, stream>>>(Vb, Vt, 2048, 1024);
        gemm256<2><<<dim3(8, 8, 4), 512, 0, stream>>>(Qb, Kb, 1024, 1024, 1024,
                                                      nullptr, nullptr, 0, Sb, 2048,
                                                      nullptr, nullptr, nullptr,
                                                      BATCH, BATCH, SZB);
        softmax_rows_b16<<<8192, 256, 0, stream>>>(Sb);
        gemm256<2><<<dim3(8, 4, 4), 512, 0, stream>>>(Sb, Vt, 2048, 2048, 2048,
                                                      nullptr, nullptr, 0, Ob, 1024,
                                                      nullptr, nullptr, nullptr,
                                                      SZB, BATCH, BATCH);
        transpose_cast_f32<<<dim3(32, 32), 256, 0, stream>>>(w_proj, wprojT, 1024, 1024);
        gemm256<3><<<dim3(32, 4), 512, 0, stream>>>(Ob, wprojT, 1024, 1024, 1024,
                                                    b_proj, out, 1024, nullptr, 0,
                                                    nullptr, nullptr, nullptr, 0, 0, 0);
    } else {
        // ---- low-memory per-batch plan (<=46 MB) ----
        u16* xbB    = (u16*)(ws);                    // reused as O per batch
        u16* QbB    = (u16*)(ws + 4194304);
        u16* KbB    = (u16*)(ws + 8388608);
        u16* VbB    = (u16*)(ws + 12582912);
        u16* VtB    = (u16*)(ws + 16777216);
        u16* Sb     = (u16*)(ws + 20971520);         // bf16 S (8.4 MB)
        u16* wqkvT  = (u16*)(ws + 37748736);
        u16* wprojT = (u16*)(ws + 44040192);
        u16* ObB    = xbB;

        transpose_cast_f32<<<dim3(96, 32), 256, 0, stream>>>(w_qkv, wqkvT, 1024, 3072);
        transpose_cast_f32<<<dim3(32, 32), 256, 0, stream>>>(w_proj, wprojT, 1024, 1024);
        for (int b = 0; b < 4; ++b) {
            cast_f32_bf16<<<1024, 256, 0, stream>>>(x + (size_t)b * BATCH, xbB, 262144);
            gemm256<0><<<dim3(8, 12), 512, 0, stream>>>(xbB, wqkvT, 1024, 1024, 1024,
                                                        b_qkv, nullptr, 0, nullptr, 0,
                                                        QbB, KbB, VbB, 0, 0, 0);
            transpose_b16<<<dim3(32, 64, 1), 256, 0, stream>>>(VbB, VtB, 2048, 1024);
            gemm256<2><<<dim3(8, 8), 512, 0, stream>>>(QbB, KbB, 1024, 1024, 1024,
                                                       nullptr, nullptr, 0, Sb, 2048,
                                                       nullptr, nullptr, nullptr, 0, 0, 0);
            softmax_rows_b16<<<2048, 256, 0, stream>>>(Sb);
            gemm256<2><<<dim3(8, 4), 512, 0, stream>>>(Sb, VtB, 2048, 2048, 2048,
                                                       nullptr, nullptr, 0, ObB, 1024,
                                                       nullptr, nullptr, nullptr, 0, 0, 0);
            gemm256<3><<<dim3(8, 4), 512, 0, stream>>>(ObB, wprojT, 1024, 1024, 1024,
                                                       b_proj, out + (size_t)b * BATCH, 1024,
                                                       nullptr, 0, nullptr, nullptr, nullptr,
                                                       0, 0, 0);
        }
    }
}

// Round 4
// 203.058 us; speedup vs baseline: 1.5223x; 1.1721x over previous
//
#include <hip/hip_runtime.h>

typedef unsigned short u16;
typedef __attribute__((ext_vector_type(8))) unsigned short u16x8;
typedef __attribute__((ext_vector_type(8))) short s16x8;
typedef __attribute__((ext_vector_type(4))) float f32x4;

__device__ __forceinline__ u16 f2bf(float f) {
    union { float f; unsigned int u; } c; c.f = f;
    unsigned int u = c.u;
    u += 0x7fffu + ((u >> 16) & 1u);   // RNE
    return (u16)(u >> 16);
}
__device__ __forceinline__ float bf2f(u16 h) {
    union { unsigned int u; float f; } c; c.u = ((unsigned int)h) << 16; return c.f;
}

// async 16B global -> LDS (dest: wave-uniform base, HW adds lane*16)
__device__ __forceinline__ void gload16(const u16* g, u16* l) {
    __builtin_amdgcn_global_load_lds(
        (const __attribute__((address_space(1))) void*)g,
        (__attribute__((address_space(3))) void*)l, 16, 0, 0);
}

// ---------------- cast fp32 -> bf16, 8 elems/thread ----------------
__global__ __launch_bounds__(256) void cast_f32_bf16(const float* __restrict__ in,
                                                     u16* __restrict__ out, int n8) {
    int i = blockIdx.x * 256 + threadIdx.x;
    if (i >= n8) return;
    const float4* p = (const float4*)in;
    float4 a = p[2 * i], b = p[2 * i + 1];
    u16x8 o;
    o[0] = f2bf(a.x); o[1] = f2bf(a.y); o[2] = f2bf(a.z); o[3] = f2bf(a.w);
    o[4] = f2bf(b.x); o[5] = f2bf(b.y); o[6] = f2bf(b.z); o[7] = f2bf(b.w);
    ((u16x8*)out)[i] = o;
}

// ---------------- transpose+cast: src fp32 [R][C] -> dst bf16 [C][R] ----------------
__global__ __launch_bounds__(256) void transpose_cast_f32(const float* __restrict__ src,
                                                          u16* __restrict__ dst, int R, int C) {
    __shared__ u16 t[32][33];
    int tx = threadIdx.x & 31, ty = threadIdx.x >> 5;
    int c0 = blockIdx.x * 32, r0 = blockIdx.y * 32;
#pragma unroll
    for (int i = 0; i < 4; ++i)
        t[ty + i * 8][tx] = f2bf(src[(size_t)(r0 + ty + i * 8) * C + c0 + tx]);
    __syncthreads();
#pragma unroll
    for (int i = 0; i < 4; ++i)
        dst[(size_t)(c0 + ty + i * 8) * R + r0 + tx] = t[tx][ty + i * 8];
}

// ---------------- transpose bf16 [R][C] -> [C][R], batched over blockIdx.z ----------------
__global__ __launch_bounds__(256) void transpose_b16(const u16* __restrict__ src,
                                                     u16* __restrict__ dst, int R, int C) {
    src += (size_t)blockIdx.z * R * C;
    dst += (size_t)blockIdx.z * R * C;
    __shared__ u16 t[32][33];
    int tx = threadIdx.x & 31, ty = threadIdx.x >> 5;
    int c0 = blockIdx.x * 32, r0 = blockIdx.y * 32;
#pragma unroll
    for (int i = 0; i < 4; ++i)
        t[ty + i * 8][tx] = src[(size_t)(r0 + ty + i * 8) * C + c0 + tx];
    __syncthreads();
#pragma unroll
    for (int i = 0; i < 4; ++i)
        dst[(size_t)(c0 + ty + i * 8) * R + r0 + tx] = t[tx][ty + i * 8];
}

// ---------------- row softmax over 2048 bf16 cols, in-place ----------------
__global__ __launch_bounds__(256) void softmax_rows_b16(u16* __restrict__ S) {
    const int t = threadIdx.x;
    u16* row = S + (size_t)blockIdx.x * 2048;
    u16x8 a = ((const u16x8*)row)[t];
    float f[8];
#pragma unroll
    for (int j = 0; j < 8; ++j) f[j] = bf2f(a[j]);
    float m = fmaxf(fmaxf(fmaxf(f[0], f[1]), fmaxf(f[2], f[3])),
                    fmaxf(fmaxf(f[4], f[5]), fmaxf(f[6], f[7])));
#pragma unroll
    for (int o = 32; o >= 1; o >>= 1) m = fmaxf(m, __shfl_xor(m, o));
    __shared__ float sm[4], ss[4];
    if ((t & 63) == 0) sm[t >> 6] = m;
    __syncthreads();
    m = fmaxf(fmaxf(sm[0], sm[1]), fmaxf(sm[2], sm[3]));
    float s = 0.f;
#pragma unroll
    for (int j = 0; j < 8; ++j) { f[j] = __expf(f[j] - m); s += f[j]; }
#pragma unroll
    for (int o = 32; o >= 1; o >>= 1) s += __shfl_xor(s, o);
    if ((t & 63) == 0) ss[t >> 6] = s;
    __syncthreads();
    s = (ss[0] + ss[1]) + (ss[2] + ss[3]);
    float inv = 1.f / s;
    u16x8 o8;
#pragma unroll
    for (int j = 0; j < 8; ++j) o8[j] = f2bf(f[j] * inv);
    ((u16x8*)row)[t] = o8;
}

// ======== 128x128 2-phase bf16 GEMM: C = A[M,K] * Bt[N,K]^T ========
// 256 thr = 4 waves (2x2), per wave 64x64 = 4x4 frags of 16x16x32. BK=64.
// LDS 64 KiB = 2 bufs x {A[128][64] | B[128][64]} -> 2 blocks/CU.
// Schedule per K-tile (catalog T3-min): STAGE(t+1 -> other buf) at TOP of iter,
// then ds_read+MFMA(t), then ONE vmcnt(0)+barrier. Loads get a full compute
// phase of flight; staging into buf o is safe (o's readers drained their
// ds_reads via data-deps before the previous barrier).
// Staging: gload16 linear dest + pre-swizzled global source col; reads XOR-swizzled.
// EPI 0: QKV split+bias (+fold 1/32 into Q)   2: bf16 store   3: bias + fp32 store
template<int EPI>
__global__ __launch_bounds__(256) void gemm128(
    const u16* __restrict__ A, const u16* __restrict__ Bt,
    int K, int ldA, int ldBt,
    const float* __restrict__ bias,
    float* __restrict__ outF, int ldOutF,
    u16* __restrict__ outH, int ldOutH,
    u16* __restrict__ Qo, u16* __restrict__ Ko, u16* __restrict__ Vo,
    size_t zA, size_t zBt, size_t zOut) {
    __shared__ u16 lds[2][16384];       // [buf][ A: 0..8191 | B: 8192..16383 ] u16
    const int tid  = threadIdx.x;
    const int lane = tid & 63;
    const int wave = tid >> 6;
    const int wrow = wave >> 1, wcol = wave & 1;
    const int lrow = lane & 15;
    const int lkg  = lane >> 4;
    const int bm0  = blockIdx.x * 128;
    const int bn0  = blockIdx.y * 128;
    A  += zA  * blockIdx.z;
    Bt += zBt * blockIdx.z;

    // staging: group g covers rows [32g, 32g+32); thread -> row 32g+(tid>>3), 16B col (tid&7)*16
    const int srow = tid >> 3;                                       // 0..31
    const int ssc  = (((tid & 7) * 16) ^ ((srow & 7) << 4)) >> 1;    // pre-swizzled elem col
    const u16* aS[4];
    const u16* bS[4];
#pragma unroll
    for (int g = 0; g < 4; ++g) {
        aS[g] = A  + (size_t)(bm0 + g * 32 + srow) * ldA  + ssc;
        bS[g] = Bt + (size_t)(bn0 + g * 32 + srow) * ldBt + ssc;
    }
    const int dst = wave * 512;         // u16; + lane*16B added by HW

#define STAGE(t, b)                                                   \
    _Pragma("unroll")                                                 \
    for (int g = 0; g < 4; ++g) {                                     \
        gload16(aS[g] + (size_t)(t) * 64, lds[b] + g * 2048 + dst);   \
        gload16(bS[g] + (size_t)(t) * 64, lds[b] + 8192 + g * 2048 + dst); \
    }

    const int sc0 = (lkg * 16) ^ ((lrow & 7) << 4);
    const int sc1 = (64 + lkg * 16) ^ ((lrow & 7) << 4);

    f32x4 acc[4][4] = {};
    const int NT = K >> 6;

    STAGE(0, 0);
    asm volatile("s_waitcnt vmcnt(0)" ::: "memory");
    __builtin_amdgcn_s_barrier();
    __builtin_amdgcn_sched_barrier(0);

    for (int t = 0; t < NT; ++t) {
        const int c = t & 1, o = c ^ 1;
        if (t + 1 < NT) STAGE(t + 1, o);          // top-of-iter: full phase of flight
        const char* base = (const char*)lds[c];
        s16x8 ra[4][2], rb[4][2];
#pragma unroll
        for (int i = 0; i < 4; ++i) {
            const char* p = base + (wrow * 64 + i * 16 + lrow) * 128;
            ra[i][0] = *(const s16x8*)(p + sc0);
            ra[i][1] = *(const s16x8*)(p + sc1);
        }
#pragma unroll
        for (int j = 0; j < 4; ++j) {
            const char* p = base + 16384 + (wcol * 64 + j * 16 + lrow) * 128;
            rb[j][0] = *(const s16x8*)(p + sc0);
            rb[j][1] = *(const s16x8*)(p + sc1);
        }
#pragma unroll
        for (int ks = 0; ks < 2; ++ks)
#pragma unroll
            for (int i = 0; i < 4; ++i)
#pragma unroll
                for (int j = 0; j < 4; ++j)
                    acc[i][j] = __builtin_amdgcn_mfma_f32_16x16x32_bf16(
                        ra[i][ks], rb[j][ks], acc[i][j], 0, 0, 0);
        asm volatile("s_waitcnt vmcnt(0)" ::: "memory");   // t+1 staged (full flight elapsed)
        __builtin_amdgcn_s_barrier();
        __builtin_amdgcn_sched_barrier(0);                 // pin next iter's ds_reads below
    }
#undef STAGE

    // ---- epilogue: C/D layout col = lane&15, row = (lane>>4)*4 + reg [m89-verified] ----
    if (zOut) outH += zOut * blockIdx.z;
#pragma unroll
    for (int i = 0; i < 4; ++i) {
        int row0 = bm0 + wrow * 64 + i * 16 + lkg * 4;
#pragma unroll
        for (int j = 0; j < 4; ++j) {
            int col = bn0 + wcol * 64 + j * 16 + lrow;
#pragma unroll
            for (int r = 0; r < 4; ++r) {
                int row = row0 + r;
                float v = acc[i][j][r];
                if constexpr (EPI == 0) {
                    v += bias[col];
                    if (col < 1024)       Qo[(size_t)row * 1024 + col] = f2bf(v * 0.03125f);
                    else if (col < 2048)  Ko[(size_t)row * 1024 + (col - 1024)] = f2bf(v);
                    else                  Vo[(size_t)row * 1024 + (col - 2048)] = f2bf(v);
                } else if constexpr (EPI == 2) {
                    outH[(size_t)row * ldOutH + col] = f2bf(v);
                } else {
                    outF[(size_t)row * ldOutF + col] = v + bias[col];
                }
            }
        }
    }
}

extern "C" void kernel_launch(void* const* d_in, const int* in_sizes, int n_in,
                              void* d_out, int out_size, void* d_ws, size_t ws_size,
                              hipStream_t stream) {
    const float* x      = (const float*)d_in[0];
    const float* w_qkv  = (const float*)d_in[1];
    const float* b_qkv  = (const float*)d_in[2];
    const float* w_proj = (const float*)d_in[3];
    const float* b_proj = (const float*)d_in[4];
    float* out = (float*)d_out;
    char* ws = (char*)d_ws;
    (void)in_sizes; (void)n_in; (void)out_size;

    const size_t MB16  = 16777216;      // bf16 [8192][1024] bytes
    const size_t BATCH = 2097152;       // per-batch elements (2048*1024)
    const size_t SZB   = 4194304;       // per-batch S elements (2048*2048)

    if (ws_size >= 85983232) {
        // ---- batched plan (83.9 MB) ----
        u16* xb     = (u16*)(ws);                    // -> Vt after QKV
        u16* Qb     = (u16*)(ws + MB16);             // -> Ob after S-GEMM
        u16* Kb     = (u16*)(ws + 2 * MB16);
        u16* Vb     = (u16*)(ws + 3 * MB16);         // -> Sb (4 batches, 33.5 MB)
        u16* wqkvT  = (u16*)(ws + 4 * MB16);         // dead after QKV; Sb overwrites
        u16* Vt     = xb;
        u16* Ob     = Qb;
        u16* Sb     = Vb;
        u16* wprojT = Kb;

        cast_f32_bf16<<<4096, 256, 0, stream>>>(x, xb, 1048576);
        transpose_cast_f32<<<dim3(96, 32), 256, 0, stream>>>(w_qkv, wqkvT, 1024, 3072);
        gemm128<0><<<dim3(64, 24), 256, 0, stream>>>(xb, wqkvT, 1024, 1024, 1024,
                                                     b_qkv, nullptr, 0, nullptr, 0,
                                                     Qb, Kb, Vb, 0, 0, 0);
        transpose_b16<<<dim3(32, 64, 4), 256, 0, stream>>>(Vb, Vt, 2048, 1024);
        gemm128<2><<<dim3(16, 16, 4), 256, 0, stream>>>(Qb, Kb, 1024, 1024, 1024,
                                                        nullptr, nullptr, 0, Sb, 2048,
                                                        nullptr, nullptr, nullptr,
                                                        BATCH, BATCH, SZB);
        softmax_rows_b16<<<8192, 256, 0, stream>>>(Sb);
        gemm128<2><<<dim3(16, 8, 4), 256, 0, stream>>>(Sb, Vt, 2048, 2048, 2048,
                                                       nullptr, nullptr, 0, Ob, 1024,
                                                       nullptr, nullptr, nullptr,
                                                       SZB, BATCH, BATCH);
        transpose_cast_f32<<<dim3(32, 32), 256, 0, stream>>>(w_proj, wprojT, 1024, 1024);
        gemm128<3><<<dim3(64, 8), 256, 0, stream>>>(Ob, wprojT, 1024, 1024, 1024,
                                                    b_proj, out, 1024, nullptr, 0,
                                                    nullptr, nullptr, nullptr, 0, 0, 0);
    } else {
        // ---- low-memory per-batch plan (<=46 MB) ----
        u16* xbB    = (u16*)(ws);                    // reused as O per batch
        u16* QbB    = (u16*)(ws + 4194304);
        u16* KbB    = (u16*)(ws + 8388608);
        u16* VbB    = (u16*)(ws + 12582912);
        u16* VtB    = (u16*)(ws + 16777216);
        u16* Sb     = (u16*)(ws + 20971520);         // bf16 S (8.4 MB)
        u16* wqkvT  = (u16*)(ws + 37748736);
        u16* wprojT = (u16*)(ws + 44040192);
        u16* ObB    = xbB;

        transpose_cast_f32<<<dim3(96, 32), 256, 0, stream>>>(w_qkv, wqkvT, 1024, 3072);
        transpose_cast_f32<<<dim3(32, 32), 256, 0, stream>>>(w_proj, wprojT, 1024, 1024);
        for (int b = 0; b < 4; ++b) {
            cast_f32_bf16<<<1024, 256, 0, stream>>>(x + (size_t)b * BATCH, xbB, 262144);
            gemm128<0><<<dim3(16, 24), 256, 0, stream>>>(xbB, wqkvT, 1024, 1024, 1024,
                                                         b_qkv, nullptr, 0, nullptr, 0,
                                                         QbB, KbB, VbB, 0, 0, 0);
            transpose_b16<<<dim3(32, 64, 1), 256, 0, stream>>>(VbB, VtB, 2048, 1024);
            gemm128<2><<<dim3(16, 16), 256, 0, stream>>>(QbB, KbB, 1024, 1024, 1024,
                                                         nullptr, nullptr, 0, Sb, 2048,
                                                         nullptr, nullptr, nullptr, 0, 0, 0);
            softmax_rows_b16<<<2048, 256, 0, stream>>>(Sb);
            gemm128<2><<<dim3(16, 8), 256, 0, stream>>>(Sb, VtB, 2048, 2048, 2048,
                                                        nullptr, nullptr, 0, ObB, 1024,
                                                        nullptr, nullptr, nullptr, 0, 0, 0);
            gemm128<3><<<dim3(16, 8), 256, 0, stream>>>(ObB, wprojT, 1024, 1024, 1024,
                                                        b_proj, out + (size_t)b * BATCH, 1024,
                                                        nullptr, 0, nullptr, nullptr, nullptr,
                                                        0, 0, 0);
        }
    }
}